// Round 4
// baseline (564.021 us; speedup 1.0000x reference)
//
#include <hip/hip_runtime.h>
#include <math.h>

#define SRATE   48000
#define NFFT    2048
#define HOP     64
#define NMELS   128
#define NFREQ   1025          // NFFT/2 + 1
#define NTGT    64
#define BATCH   32
#define NFRAMES 751           // 1 + 48000/64
#define MELSZ   (NMELS * NFRAMES)   // 96128
#define NCHUNK  751           // MELSZ / 128
#define CPB     3             // chunks per block in diff kernel
#define NB_B    ((NCHUNK + CPB - 1) / CPB)   // 251
#define PADW    132           // padded LDS row stride (floats) in diff kernel

// ---------------------------------------------------------------------------
// Kernel T: transpose fb (NFREQ x NMELS) -> fbT (NMELS x NFREQ) and find the
// exact nonzero f-range of each mel filter (exact sparsity from input data).
// ---------------------------------------------------------------------------
__global__ __launch_bounds__(256) void fbt_kernel(
    const float* __restrict__ fb, float* __restrict__ fbT,
    int* __restrict__ fs, int* __restrict__ fe) {
  int m = blockIdx.x;
  int tid = threadIdx.x;
  __shared__ int smin[256], smax[256];
  int lmin = NFREQ, lmax = -1;
  for (int f = tid; f < NFREQ; f += 256) {
    float v = fb[f * NMELS + m];
    fbT[m * NFREQ + f] = v;
    if (v > 0.0f) {
      if (f < lmin) lmin = f;
      if (f > lmax) lmax = f;
    }
  }
  smin[tid] = lmin;
  smax[tid] = lmax;
  __syncthreads();
  for (int off = 128; off > 0; off >>= 1) {
    if (tid < off) {
      smin[tid] = min(smin[tid], smin[tid + off]);
      smax[tid] = max(smax[tid], smax[tid + off]);
    }
    __syncthreads();
  }
  if (tid == 0) {
    fs[m] = smin[0];
    fe[m] = smax[0];
  }
}

// ---------------------------------------------------------------------------
// Kernel A: one block (256 thr) per frame. Reflect-pad + Hann window, radix-2
// DIT FFT (2048, complex, imag=0 in) in LDS, power spectrum, sparse mel
// projection. mel layout: [b][m][t] to match mel_targets.
// ---------------------------------------------------------------------------
__global__ __launch_bounds__(256) void melspec_kernel(
    const float* __restrict__ x, const float* __restrict__ fbT,
    const int* __restrict__ fs, const int* __restrict__ fe,
    float* __restrict__ mel) {
  __shared__ float re[NFFT];
  __shared__ float im[NFFT];
  __shared__ float twc[NFFT / 2];
  __shared__ float tws[NFFT / 2];
  __shared__ float pw[NFREQ];

  int tid = threadIdx.x;
  int fid = blockIdx.x;
  int b = fid / NFRAMES;
  int t = fid - b * NFRAMES;
  const float* xb = x + (size_t)b * SRATE;

  // twiddle table: W[k] = exp(-i * pi * k / 1024), k < 1024
  for (int k = tid; k < NFFT / 2; k += 256) {
    float sv, cv;
    sincosf(-(float)(M_PI / 1024.0) * (float)k, &sv, &cv);
    twc[k] = cv;
    tws[k] = sv;
  }
  // load + reflect pad + window, store at bit-reversed index
  for (int i = tid; i < NFFT; i += 256) {
    int pos = t * HOP + i - NFFT / 2;
    if (pos < 0) pos = -pos;
    else if (pos >= SRATE) pos = 2 * SRATE - 2 - pos;
    float w = 0.5f - 0.5f * cosf((float)(2.0 * M_PI / NFFT) * (float)i);
    int r = (int)(__brev((unsigned)i) >> 21);
    re[r] = xb[pos] * w;
    im[r] = 0.0f;
  }
  __syncthreads();

  // 11 radix-2 DIT stages
  for (int s = 1; s <= 11; ++s) {
    int h = 1 << (s - 1);
    int shift = 11 - s;
    #pragma unroll
    for (int it = 0; it < 4; ++it) {
      int j = tid + it * 256;
      int pos = j & (h - 1);
      int i0 = ((j >> (s - 1)) << s) + pos;
      int i1 = i0 + h;
      int k = pos << shift;
      float wc = twc[k], ws_ = tws[k];   // wc = cos(th), ws_ = sin(-th)
      float r1 = re[i1], q1 = im[i1];
      float tre = wc * r1 - ws_ * q1;
      float tim = wc * q1 + ws_ * r1;
      float r0 = re[i0], q0 = im[i0];
      re[i0] = r0 + tre;
      im[i0] = q0 + tim;
      re[i1] = r0 - tre;
      im[i1] = q0 - tim;
    }
    __syncthreads();
  }

  // power spectrum (only need |X|^2 so twiddle sign conv is irrelevant)
  for (int f = tid; f < NFREQ; f += 256) pw[f] = re[f] * re[f] + im[f] * im[f];
  __syncthreads();

  // sparse mel projection: thread m gathers its filter's nonzero bins
  if (tid < NMELS) {
    int m = tid;
    int f0 = fs[m], f1 = fe[m];
    const float* col = fbT + (size_t)m * NFREQ;
    float acc = 0.0f;
    for (int f = f0; f <= f1; ++f) acc += pw[f] * col[f];
    mel[(size_t)b * MELSZ + m * NFRAMES + t] = acc;
  }
}

// ---------------------------------------------------------------------------
// Kernel B: L1-distance partials. Each block handles CPB chunks of 128
// flattened (m,t) positions for all 32x64 (b,k) pairs. Deterministic partial
// sums to workspace (no atomics). LDS rows padded to 132 to spread banks.
// ---------------------------------------------------------------------------
__global__ __launch_bounds__(256) void diff_kernel(
    const float* __restrict__ mel, const float* __restrict__ tgt,
    float* __restrict__ part) {
  __shared__ float mel_s[BATCH * PADW];
  __shared__ float tgt_s[NTGT * PADW];
  int tid = threadIdx.x;
  int b = tid >> 3;       // 0..31
  int kb = tid & 7;       // 0..7, owns k = kb + 8*i

  float acc[8];
  #pragma unroll
  for (int i = 0; i < 8; ++i) acc[i] = 0.0f;

  for (int cc = 0; cc < CPB; ++cc) {
    int c = blockIdx.x * CPB + cc;
    if (c >= NCHUNK) break;           // uniform across block
    __syncthreads();                  // protect LDS reuse across iterations
    // stage mel chunk: 32 rows x 128 floats (32 float4 per row)
    for (int q = tid; q < BATCH * 32; q += 256) {
      int row = q >> 5, c4 = q & 31;
      float4 v = *(const float4*)(mel + (size_t)row * MELSZ + c * 128 + c4 * 4);
      *(float4*)(&mel_s[row * PADW + c4 * 4]) = v;
    }
    // stage target chunk: 64 rows x 128 floats
    for (int q = tid; q < NTGT * 32; q += 256) {
      int row = q >> 5, c4 = q & 31;
      float4 v = *(const float4*)(tgt + (size_t)row * MELSZ + c * 128 + c4 * 4);
      *(float4*)(&tgt_s[row * PADW + c4 * 4]) = v;
    }
    __syncthreads();
    for (int j4 = 0; j4 < 32; ++j4) {
      float4 mv = *(const float4*)(&mel_s[b * PADW + j4 * 4]);
      #pragma unroll
      for (int i = 0; i < 8; ++i) {
        int k = kb + (i << 3);
        float4 tv = *(const float4*)(&tgt_s[k * PADW + j4 * 4]);
        acc[i] += fabsf(mv.x - tv.x) + fabsf(mv.y - tv.y) +
                  fabsf(mv.z - tv.z) + fabsf(mv.w - tv.w);
      }
    }
  }

  #pragma unroll
  for (int i = 0; i < 8; ++i)
    part[(size_t)blockIdx.x * 2048 + b * 64 + kb + (i << 3)] = acc[i];
}

// ---------------------------------------------------------------------------
// Kernel C: reduce partials -> diffs (mean), then min over 64 targets.
// 8 blocks x 256 threads cover all 2048 (b,k) pairs.
// ---------------------------------------------------------------------------
__global__ __launch_bounds__(256) void reduce_kernel(
    const float* __restrict__ part, float* __restrict__ out) {
  __shared__ float ds[256];
  int tid = threadIdx.x;
  int p = blockIdx.x * 256 + tid;
  float s = 0.0f;
  for (int bb = 0; bb < NB_B; ++bb) s += part[(size_t)bb * 2048 + p];
  ds[tid] = s * (1.0f / (float)MELSZ);
  __syncthreads();
  if (tid < 4) {
    float mn = ds[tid * 64];
    #pragma unroll
    for (int kk = 1; kk < 64; ++kk) mn = fminf(mn, ds[tid * 64 + kk]);
    out[blockIdx.x * 4 + tid] = mn;
  }
}

// ---------------------------------------------------------------------------
extern "C" void kernel_launch(void* const* d_in, const int* in_sizes, int n_in,
                              void* d_out, int out_size, void* d_ws, size_t ws_size,
                              hipStream_t stream) {
  const float* x   = (const float*)d_in[0];   // (32, 48000)
  const float* tgt = (const float*)d_in[1];   // (64, 128, 751)
  const float* fb  = (const float*)d_in[2];   // (1025, 128)
  float* out = (float*)d_out;                 // (32,)

  char* ws = (char*)d_ws;
  size_t off = 0;
  float* fbT = (float*)(ws + off);
  off += ((size_t)NMELS * NFREQ * sizeof(float) + 255) & ~(size_t)255;
  int* fs = (int*)(ws + off); off += 1024;
  int* fe = (int*)(ws + off); off += 1024;
  float* mel = (float*)(ws + off);
  off += (size_t)BATCH * MELSZ * sizeof(float);
  float* part = (float*)(ws + off);
  off += (size_t)NB_B * 2048 * sizeof(float);

  fbt_kernel<<<NMELS, 256, 0, stream>>>(fb, fbT, fs, fe);
  melspec_kernel<<<BATCH * NFRAMES, 256, 0, stream>>>(x, fbT, fs, fe, mel);
  diff_kernel<<<NB_B, 256, 0, stream>>>(mel, tgt, part);
  reduce_kernel<<<8, 256, 0, stream>>>(part, out);
}

// Round 10
// 366.519 us; speedup vs baseline: 1.5389x; 1.5389x over previous
//
#include <hip/hip_runtime.h>
#include <math.h>

#define SRATE   48000
#define NFFT    2048
#define HOP     64
#define NMELS   128
#define NFREQ   1025          // NFFT/2 + 1
#define NTGT    64
#define BATCH   32
#define NFRAMES 751           // 1 + 48000/64
#define NPAIRS  376           // ceil(751/2): 2 real frames per complex FFT
#define MELSZ   (NMELS * NFRAMES)   // 96128
#define NCHUNK  751           // MELSZ / 128
#define CPB     3             // chunks per block in diff kernel
#define NB_B    ((NCHUNK + CPB - 1) / CPB)   // 251
#define PADW    132           // padded LDS row stride (floats) in diff kernel

// Padded LDS index: injective, verified <=2 lanes/bank for every Stockham
// round's read/write pattern (L = 1,2,8,32,128,512) and for linear scans.
__device__ __forceinline__ int SP(int a) { return a + 5 * (a >> 5); }
#define SBUF 2363            // SP(2047)+1
// SP(t + 512m) = SP(t) + 592m  (512 = 16*32, exact)

// ---------------------------------------------------------------------------
// Setup kernel: window table + twiddle table (cos/sin of -2*pi*n/2048).
// ---------------------------------------------------------------------------
__global__ __launch_bounds__(256) void tab_kernel(
    float* __restrict__ wtab, float* __restrict__ gtwc, float* __restrict__ gtws) {
  int i = blockIdx.x * 256 + threadIdx.x;
  if (i < NFFT)
    wtab[i] = 0.5f - 0.5f * cosf((float)(2.0 * M_PI / NFFT) * (float)i);
  if (i < 512) {
    float sv, cv;
    sincosf(-(float)(2.0 * M_PI / NFFT) * (float)i, &sv, &cv);
    gtwc[i] = cv;
    gtws[i] = sv;
  }
}

// ---------------------------------------------------------------------------
// Kernel T: transpose fb (NFREQ x NMELS) -> fbT (NMELS x NFREQ) and find the
// exact nonzero f-range of each mel filter.
// ---------------------------------------------------------------------------
__global__ __launch_bounds__(256) void fbt_kernel(
    const float* __restrict__ fb, float* __restrict__ fbT,
    int* __restrict__ fs, int* __restrict__ fe) {
  int m = blockIdx.x;
  int tid = threadIdx.x;
  __shared__ int smin[256], smax[256];
  int lmin = NFREQ, lmax = -1;
  for (int f = tid; f < NFREQ; f += 256) {
    float v = fb[f * NMELS + m];
    fbT[m * NFREQ + f] = v;
    if (v > 0.0f) {
      if (f < lmin) lmin = f;
      if (f > lmax) lmax = f;
    }
  }
  smin[tid] = lmin;
  smax[tid] = lmax;
  __syncthreads();
  for (int off = 128; off > 0; off >>= 1) {
    if (tid < off) {
      smin[tid] = min(smin[tid], smin[tid + off]);
      smax[tid] = max(smax[tid], smax[tid + off]);
    }
    __syncthreads();
  }
  if (tid == 0) {
    fs[m] = smin[0];
    fe[m] = smax[0];
  }
}

// ---------------------------------------------------------------------------
// One Stockham radix-4 round. Invariant: src[j*L+k] = DFT_L of the residue-j
// subsequence (step N/L) at freq k. Merges residues j, j+N/4L, j+2N/4L,
// j+3N/4L. Reads linear (t + m*512 -> SP + 592m); writes j*4L + k + r*L.
// ---------------------------------------------------------------------------
template<int L>
__device__ __forceinline__ void radix4_round(
    const float* __restrict__ sre, const float* __restrict__ sim,
    float* __restrict__ dre, float* __restrict__ dim_,
    const float* __restrict__ twc, const float* __restrict__ tws, int tid) {
  constexpr int LOG2L = (L == 2) ? 1 : (L == 8) ? 3 : (L == 32) ? 5
                      : (L == 128) ? 7 : 9;
  constexpr int TS = 512 / L;   // twiddle stride: W_{4L}^k = W_2048^{k*TS}
  #pragma unroll
  for (int i = 0; i < 2; ++i) {
    int t = tid + i * 256;                 // butterfly id, t < 512
    int k = t & (L - 1);
    int j = t >> LOG2L;
    int nt = SP(k * TS);
    float wc1 = twc[nt], ws1 = tws[nt];
    float wc2 = wc1 * wc1 - ws1 * ws1, ws2 = 2.0f * wc1 * ws1;
    float wc3 = wc2 * wc1 - ws2 * ws1, ws3 = wc2 * ws1 + ws2 * wc1;
    int rb = SP(t);
    float u0r = sre[rb],        u0i = sim[rb];
    float u1r = sre[rb + 592],  u1i = sim[rb + 592];
    float u2r = sre[rb + 1184], u2i = sim[rb + 1184];
    float u3r = sre[rb + 1776], u3i = sim[rb + 1776];
    float a1r = wc1 * u1r - ws1 * u1i, a1i = wc1 * u1i + ws1 * u1r;
    float a2r = wc2 * u2r - ws2 * u2i, a2i = wc2 * u2i + ws2 * u2r;
    float a3r = wc3 * u3r - ws3 * u3i, a3i = wc3 * u3i + ws3 * u3r;
    float s0r = u0r + a2r, s0i = u0i + a2i;
    float d0r = u0r - a2r, d0i = u0i - a2i;
    float s1r = a1r + a3r, s1i = a1i + a3i;
    float d1r = a1r - a3r, d1i = a1i - a3i;
    int wb = (j << (LOG2L + 2)) + k;
    int o0 = SP(wb), o1 = SP(wb + L), o2 = SP(wb + 2 * L), o3 = SP(wb + 3 * L);
    // X[k+0L]=s0+s1; X[k+1L]=d0-i*d1; X[k+2L]=s0-s1; X[k+3L]=d0+i*d1
    dre[o0] = s0r + s1r;  dim_[o0] = s0i + s1i;
    dre[o1] = d0r + d1i;  dim_[o1] = d0i - d1r;
    dre[o2] = s0r - s1r;  dim_[o2] = s0i - s1i;
    dre[o3] = d0r - d1i;  dim_[o3] = d0i + d1r;
  }
}

// ---------------------------------------------------------------------------
// Kernel A: one block per (batch, frame-pair). Two real frames packed into
// one complex Stockham FFT (radix-2 then 5x radix-4, no bit-reversal, padded
// LDS => no bank conflicts). Conjugate-symmetry unpack directly to powers,
// then sparse mel projection for both frames.
// ---------------------------------------------------------------------------
__global__ __launch_bounds__(256) void melspec_kernel(
    const float* __restrict__ x, const float* __restrict__ fbT,
    const int* __restrict__ fs, const int* __restrict__ fe,
    const float* __restrict__ wtab, const float* __restrict__ gtwc,
    const float* __restrict__ gtws, float* __restrict__ mel) {
  __shared__ float lds[1180 + 4 * SBUF];   // 42528 B
  float* twc = lds;                        // 590
  float* tws = lds + 590;                  // 590
  float* reA = lds + 1180;
  float* imA = lds + 1180 + SBUF;
  float* reB = lds + 1180 + 2 * SBUF;
  float* imB = lds + 1180 + 3 * SBUF;

  int tid = threadIdx.x;
  int b = blockIdx.x / NPAIRS;
  int pair = blockIdx.x - b * NPAIRS;
  int t0 = pair * 2;
  bool has2 = (t0 + 1) < NFRAMES;
  const float* xb = x + (size_t)b * SRATE;

  // stage twiddles into padded LDS
  for (int n = tid; n < 512; n += 256) {
    twc[SP(n)] = gtwc[n];
    tws[SP(n)] = gtws[n];
  }
  // load both frames: reflect-pad + window; natural order, linear LDS writes
  for (int i = tid; i < NFFT; i += 256) {
    float w = wtab[i];
    int p0 = t0 * HOP + i - NFFT / 2;
    p0 = p0 < 0 ? -p0 : (p0 >= SRATE ? 2 * SRATE - 2 - p0 : p0);
    int p1 = (t0 + 1) * HOP + i - NFFT / 2;
    p1 = p1 < 0 ? -p1 : (p1 >= SRATE ? 2 * SRATE - 2 - p1 : p1);
    int s = SP(i);
    reA[s] = xb[p0] * w;
    imA[s] = has2 ? xb[p1] * w : 0.0f;
  }
  __syncthreads();

  // radix-2 round (L=1, w=1): A -> B
  #pragma unroll
  for (int i = 0; i < 4; ++i) {
    int t = tid + i * 256;
    int s0 = SP(t);
    float ur = reA[s0], ui = imA[s0];
    float vr = reA[s0 + 1184], vi = imA[s0 + 1184];   // SP(t+1024)
    int w0 = SP(2 * t);                               // SP(2t+1) = w0+1
    reB[w0] = ur + vr;     imB[w0] = ui + vi;
    reB[w0 + 1] = ur - vr; imB[w0 + 1] = ui - vi;
  }
  __syncthreads();
  radix4_round<2>(reB, imB, reA, imA, twc, tws, tid);   __syncthreads();
  radix4_round<8>(reA, imA, reB, imB, twc, tws, tid);   __syncthreads();
  radix4_round<32>(reB, imB, reA, imA, twc, tws, tid);  __syncthreads();
  radix4_round<128>(reA, imA, reB, imB, twc, tws, tid); __syncthreads();
  radix4_round<512>(reB, imB, reA, imA, twc, tws, tid); __syncthreads();
  // final natural-order spectrum Z in A

  // conjugate-symmetry unpack -> powers of both frames (B buffer is free)
  for (int k = tid; k < NFREQ; k += 256) {
    int ka = SP(k), kb = SP((NFFT - k) & (NFFT - 1));
    float a = reA[ka], bb = imA[ka];
    float c = reA[kb], d = imA[kb];
    float e1 = a + c, f1 = bb - d;     // 2*X1[k]
    float e2 = bb + d, f2 = a - c;     // 2*X2[k] (re,im swapped-safe: power)
    reB[k] = 0.25f * (e1 * e1 + f1 * f1);
    imB[k] = 0.25f * (e2 * e2 + f2 * f2);
  }
  __syncthreads();

  // sparse mel projection: 256 threads = 2 frames x 128 mels
  int fr = tid >> 7, m = tid & 127;
  int tt = t0 + fr;
  if (tt < NFRAMES) {
    int f0 = fs[m], f1 = fe[m];
    const float* col = fbT + (size_t)m * NFREQ;
    const float* pw = fr ? imB : reB;
    float acc = 0.0f;
    for (int f = f0; f <= f1; ++f) acc += pw[f] * col[f];
    mel[(size_t)b * MELSZ + m * NFRAMES + tt] = acc;
  }
}

// ---------------------------------------------------------------------------
// Kernel B: L1-distance partials (unchanged).
// ---------------------------------------------------------------------------
__global__ __launch_bounds__(256) void diff_kernel(
    const float* __restrict__ mel, const float* __restrict__ tgt,
    float* __restrict__ part) {
  __shared__ float mel_s[BATCH * PADW];
  __shared__ float tgt_s[NTGT * PADW];
  int tid = threadIdx.x;
  int b = tid >> 3;
  int kb = tid & 7;

  float acc[8];
  #pragma unroll
  for (int i = 0; i < 8; ++i) acc[i] = 0.0f;

  for (int cc = 0; cc < CPB; ++cc) {
    int c = blockIdx.x * CPB + cc;
    if (c >= NCHUNK) break;
    __syncthreads();
    for (int q = tid; q < BATCH * 32; q += 256) {
      int row = q >> 5, c4 = q & 31;
      float4 v = *(const float4*)(mel + (size_t)row * MELSZ + c * 128 + c4 * 4);
      *(float4*)(&mel_s[row * PADW + c4 * 4]) = v;
    }
    for (int q = tid; q < NTGT * 32; q += 256) {
      int row = q >> 5, c4 = q & 31;
      float4 v = *(const float4*)(tgt + (size_t)row * MELSZ + c * 128 + c4 * 4);
      *(float4*)(&tgt_s[row * PADW + c4 * 4]) = v;
    }
    __syncthreads();
    for (int j4 = 0; j4 < 32; ++j4) {
      float4 mv = *(const float4*)(&mel_s[b * PADW + j4 * 4]);
      #pragma unroll
      for (int i = 0; i < 8; ++i) {
        int k = kb + (i << 3);
        float4 tv = *(const float4*)(&tgt_s[k * PADW + j4 * 4]);
        acc[i] += fabsf(mv.x - tv.x) + fabsf(mv.y - tv.y) +
                  fabsf(mv.z - tv.z) + fabsf(mv.w - tv.w);
      }
    }
  }

  #pragma unroll
  for (int i = 0; i < 8; ++i)
    part[(size_t)blockIdx.x * 2048 + b * 64 + kb + (i << 3)] = acc[i];
}

// ---------------------------------------------------------------------------
// Kernel C: reduce partials -> diffs (mean), min over targets (unchanged).
// ---------------------------------------------------------------------------
__global__ __launch_bounds__(256) void reduce_kernel(
    const float* __restrict__ part, float* __restrict__ out) {
  __shared__ float ds[256];
  int tid = threadIdx.x;
  int p = blockIdx.x * 256 + tid;
  float s = 0.0f;
  for (int bb = 0; bb < NB_B; ++bb) s += part[(size_t)bb * 2048 + p];
  ds[tid] = s * (1.0f / (float)MELSZ);
  __syncthreads();
  if (tid < 4) {
    float mn = ds[tid * 64];
    #pragma unroll
    for (int kk = 1; kk < 64; ++kk) mn = fminf(mn, ds[tid * 64 + kk]);
    out[blockIdx.x * 4 + tid] = mn;
  }
}

// ---------------------------------------------------------------------------
extern "C" void kernel_launch(void* const* d_in, const int* in_sizes, int n_in,
                              void* d_out, int out_size, void* d_ws, size_t ws_size,
                              hipStream_t stream) {
  const float* x   = (const float*)d_in[0];   // (32, 48000)
  const float* tgt = (const float*)d_in[1];   // (64, 128, 751)
  const float* fb  = (const float*)d_in[2];   // (1025, 128)
  float* out = (float*)d_out;                 // (32,)

  char* ws = (char*)d_ws;
  size_t off = 0;
  float* fbT = (float*)(ws + off);
  off += ((size_t)NMELS * NFREQ * sizeof(float) + 255) & ~(size_t)255;
  int* fs = (int*)(ws + off); off += 1024;
  int* fe = (int*)(ws + off); off += 1024;
  float* wtab = (float*)(ws + off); off += NFFT * sizeof(float);
  float* gtwc = (float*)(ws + off); off += 512 * sizeof(float);
  float* gtws = (float*)(ws + off); off += 512 * sizeof(float);
  float* mel = (float*)(ws + off);
  off += (size_t)BATCH * MELSZ * sizeof(float);
  float* part = (float*)(ws + off);
  off += (size_t)NB_B * 2048 * sizeof(float);

  tab_kernel<<<8, 256, 0, stream>>>(wtab, gtwc, gtws);
  fbt_kernel<<<NMELS, 256, 0, stream>>>(fb, fbT, fs, fe);
  melspec_kernel<<<BATCH * NPAIRS, 256, 0, stream>>>(
      x, fbT, fs, fe, wtab, gtwc, gtws, mel);
  diff_kernel<<<NB_B, 256, 0, stream>>>(mel, tgt, part);
  reduce_kernel<<<8, 256, 0, stream>>>(part, out);
}

// Round 11
// 291.287 us; speedup vs baseline: 1.9363x; 1.2583x over previous
//
#include <hip/hip_runtime.h>
#include <math.h>

#define SRATE   48000
#define NFFT    2048
#define N1      1024          // half-size complex FFT per real frame
#define HOP     64
#define NMELS   128
#define NFREQ   1025          // NFFT/2 + 1
#define NTGT    64
#define BATCH   32
#define NFRAMES 751           // 1 + 48000/64
#define MELSZ   (NMELS * NFRAMES)   // 96128
#define NCHUNK  751           // MELSZ / 128
#define CPB     1             // chunks per block in diff kernel (751 blocks ~3/CU)
#define NB_B    ((NCHUNK + CPB - 1) / CPB)   // 751
#define PADW    132           // padded LDS row stride (floats) in diff kernel

// Padded LDS index (verified structure from the 2048 kernel, absmax 0.0):
// injective; reads t+256m -> SP(t)+296m (lanes stride-1, conflict-free);
// writes analyzed <=3-way worst (round L=16), rest <=2-way (free).
__device__ __forceinline__ int SP(int a) { return a + 5 * (a >> 5); }
#define SBUF1 1179            // SP(1023)+1
__device__ __forceinline__ int TP(int a) { return a + (a >> 5); }
#define TWP   263             // TP(255)+1

// ---------------------------------------------------------------------------
// Setup kernel: window table (2048) + twiddle table W_2048^k, k<=1024.
// ---------------------------------------------------------------------------
__global__ __launch_bounds__(256) void tab_kernel(
    float* __restrict__ wtab, float* __restrict__ gtwc, float* __restrict__ gtws) {
  int i = blockIdx.x * 256 + threadIdx.x;
  if (i < NFFT)
    wtab[i] = 0.5f - 0.5f * cosf((float)(2.0 * M_PI / NFFT) * (float)i);
  if (i <= 1024) {
    float sv, cv;
    sincosf(-(float)(2.0 * M_PI / NFFT) * (float)i, &sv, &cv);
    gtwc[i] = cv;
    gtws[i] = sv;
  }
}

// ---------------------------------------------------------------------------
// Kernel T: transpose fb -> fbT and exact nonzero f-range per mel filter.
// ---------------------------------------------------------------------------
__global__ __launch_bounds__(256) void fbt_kernel(
    const float* __restrict__ fb, float* __restrict__ fbT,
    int* __restrict__ fs, int* __restrict__ fe) {
  int m = blockIdx.x;
  int tid = threadIdx.x;
  __shared__ int smin[256], smax[256];
  int lmin = NFREQ, lmax = -1;
  for (int f = tid; f < NFREQ; f += 256) {
    float v = fb[f * NMELS + m];
    fbT[m * NFREQ + f] = v;
    if (v > 0.0f) {
      if (f < lmin) lmin = f;
      if (f > lmax) lmax = f;
    }
  }
  smin[tid] = lmin;
  smax[tid] = lmax;
  __syncthreads();
  for (int off = 128; off > 0; off >>= 1) {
    if (tid < off) {
      smin[tid] = min(smin[tid], smin[tid + off]);
      smax[tid] = max(smax[tid], smax[tid + off]);
    }
    __syncthreads();
  }
  if (tid == 0) {
    fs[m] = smin[0];
    fe[m] = smax[0];
  }
}

// ---------------------------------------------------------------------------
// One Stockham radix-4 round for N=1024, 256 threads, 1 butterfly/thread.
// Twiddle W_{4L}^k = W_1024^{k*(256/L)} from padded LDS table; w^2, w^3
// chained in-register. L=1 round is twiddle-free.
// ---------------------------------------------------------------------------
template<int L>
__device__ __forceinline__ void r4_1024(
    const float* __restrict__ sre, const float* __restrict__ sim,
    float* __restrict__ dre, float* __restrict__ dim_,
    const float* __restrict__ twc, const float* __restrict__ tws, int t) {
  constexpr int LOG2L = (L == 1) ? 0 : (L == 4) ? 2 : (L == 16) ? 4
                      : (L == 64) ? 6 : 8;
  constexpr int TS = 256 / L;
  int k = t & (L - 1);
  int j = t >> LOG2L;
  int rb = SP(t);
  float u0r = sre[rb],       u0i = sim[rb];
  float u1r = sre[rb + 296], u1i = sim[rb + 296];
  float u2r = sre[rb + 592], u2i = sim[rb + 592];
  float u3r = sre[rb + 888], u3i = sim[rb + 888];
  float a1r, a1i, a2r, a2i, a3r, a3i;
  if (L == 1) {
    a1r = u1r; a1i = u1i; a2r = u2r; a2i = u2i; a3r = u3r; a3i = u3i;
  } else {
    int tp = TP(k * TS);
    float wc1 = twc[tp], ws1 = tws[tp];
    float wc2 = wc1 * wc1 - ws1 * ws1, ws2 = 2.0f * wc1 * ws1;
    float wc3 = wc2 * wc1 - ws2 * ws1, ws3 = wc2 * ws1 + ws2 * wc1;
    a1r = wc1 * u1r - ws1 * u1i; a1i = wc1 * u1i + ws1 * u1r;
    a2r = wc2 * u2r - ws2 * u2i; a2i = wc2 * u2i + ws2 * u2r;
    a3r = wc3 * u3r - ws3 * u3i; a3i = wc3 * u3i + ws3 * u3r;
  }
  float s0r = u0r + a2r, s0i = u0i + a2i;
  float d0r = u0r - a2r, d0i = u0i - a2i;
  float s1r = a1r + a3r, s1i = a1i + a3i;
  float d1r = a1r - a3r, d1i = a1i - a3i;
  int wb = (j << (LOG2L + 2)) + k;
  int o0 = SP(wb), o1 = SP(wb + L), o2 = SP(wb + 2 * L), o3 = SP(wb + 3 * L);
  dre[o0] = s0r + s1r;  dim_[o0] = s0i + s1i;
  dre[o1] = d0r + d1i;  dim_[o1] = d0i - d1r;
  dre[o2] = s0r - s1r;  dim_[o2] = s0i - s1i;
  dre[o3] = d0r - d1i;  dim_[o3] = d0i + d1r;
}

// ---------------------------------------------------------------------------
// Kernel A: one block per (batch, frame). Even/odd-packed 1024-pt complex
// Stockham FFT (20.9 KB LDS -> 7 blocks/CU), conjugate-symmetry post-twiddle
// unpack straight to powers, sparse mel projection (2 threads per filter).
// ---------------------------------------------------------------------------
__global__ __launch_bounds__(256) void melspec_kernel(
    const float* __restrict__ x, const float* __restrict__ fbT,
    const int* __restrict__ fs, const int* __restrict__ fe,
    const float* __restrict__ wtab, const float* __restrict__ gtwc,
    const float* __restrict__ gtws, float* __restrict__ mel) {
  __shared__ float lds[4 * SBUF1 + 2 * TWP];   // 20968 B
  float* reA  = lds;
  float* imA  = lds + SBUF1;
  float* reB  = lds + 2 * SBUF1;
  float* imB  = lds + 3 * SBUF1;
  float* tw1c = lds + 4 * SBUF1;
  float* tw1s = lds + 4 * SBUF1 + TWP;

  int tid = threadIdx.x;
  int b = blockIdx.x / NFRAMES;
  int t = blockIdx.x - b * NFRAMES;
  const float* xb = x + (size_t)b * SRATE;

  // stage round twiddles: W_1024^j = W_2048^{2j}, j<256, padded
  {
    int j = tid;
    tw1c[TP(j)] = gtwc[2 * j];
    tw1s[TP(j)] = gtws[2 * j];
  }
  // load frame: z[n] = xw[2n] + i*xw[2n+1] (reflect-pad + Hann)
  for (int n = tid; n < N1; n += 256) {
    int i0 = 2 * n, i1 = 2 * n + 1;
    int p0 = t * HOP + i0 - NFFT / 2;
    p0 = p0 < 0 ? -p0 : (p0 >= SRATE ? 2 * SRATE - 2 - p0 : p0);
    int p1 = t * HOP + i1 - NFFT / 2;
    p1 = p1 < 0 ? -p1 : (p1 >= SRATE ? 2 * SRATE - 2 - p1 : p1);
    int s = SP(n);
    reA[s] = xb[p0] * wtab[i0];
    imA[s] = xb[p1] * wtab[i1];
  }
  __syncthreads();

  r4_1024<1>(reA, imA, reB, imB, tw1c, tw1s, tid);   __syncthreads();
  r4_1024<4>(reB, imB, reA, imA, tw1c, tw1s, tid);   __syncthreads();
  r4_1024<16>(reA, imA, reB, imB, tw1c, tw1s, tid);  __syncthreads();
  r4_1024<64>(reB, imB, reA, imA, tw1c, tw1s, tid);  __syncthreads();
  r4_1024<256>(reA, imA, reB, imB, tw1c, tw1s, tid); __syncthreads();
  // natural-order Z in B

  // rfft unpack -> power, k = 0..1024 (pw stored plain-indexed in reA)
  for (int k = tid; k <= 1024; k += 256) {
    int ka = SP(k & (N1 - 1)), kb = SP((N1 - k) & (N1 - 1));
    float Zar = reB[ka], Zai = imB[ka];
    float Zbr = reB[kb], Zbi = imB[kb];
    float Xer  = 0.5f * (Zar + Zbr), Xei = 0.5f * (Zai - Zbi);
    float Xor_ = 0.5f * (Zai + Zbi), Xoi = 0.5f * (Zbr - Zar);
    float wc = gtwc[k], ws = gtws[k];
    float Xr = Xer + wc * Xor_ - ws * Xoi;
    float Xi = Xei + wc * Xoi + ws * Xor_;
    reA[k] = Xr * Xr + Xi * Xi;
  }
  __syncthreads();

  // sparse mel projection: 2 threads per filter, shuffle-combine
  int m = tid >> 1, half = tid & 1;
  int f0 = fs[m], f1 = fe[m];
  int mid = f0 + ((f1 - f0 + 1) >> 1);
  int lo = half ? mid : f0;
  int hi = half ? f1 : mid - 1;
  const float* col = fbT + (size_t)m * NFREQ;
  float acc = 0.0f;
  for (int f = lo; f <= hi; ++f) acc += reA[f] * col[f];
  acc += __shfl_xor(acc, 1);
  if (!half) mel[(size_t)b * MELSZ + m * NFRAMES + t] = acc;
}

// ---------------------------------------------------------------------------
// Kernel B: L1-distance partials. CPB=1 -> 751 blocks (~3/CU) so staging
// overlaps compute across resident blocks.
// ---------------------------------------------------------------------------
__global__ __launch_bounds__(256) void diff_kernel(
    const float* __restrict__ mel, const float* __restrict__ tgt,
    float* __restrict__ part) {
  __shared__ float mel_s[BATCH * PADW];
  __shared__ float tgt_s[NTGT * PADW];
  int tid = threadIdx.x;
  int b = tid >> 3;
  int kb = tid & 7;

  float acc[8];
  #pragma unroll
  for (int i = 0; i < 8; ++i) acc[i] = 0.0f;

  for (int cc = 0; cc < CPB; ++cc) {
    int c = blockIdx.x * CPB + cc;
    if (c >= NCHUNK) break;
    __syncthreads();
    for (int q = tid; q < BATCH * 32; q += 256) {
      int row = q >> 5, c4 = q & 31;
      float4 v = *(const float4*)(mel + (size_t)row * MELSZ + c * 128 + c4 * 4);
      *(float4*)(&mel_s[row * PADW + c4 * 4]) = v;
    }
    for (int q = tid; q < NTGT * 32; q += 256) {
      int row = q >> 5, c4 = q & 31;
      float4 v = *(const float4*)(tgt + (size_t)row * MELSZ + c * 128 + c4 * 4);
      *(float4*)(&tgt_s[row * PADW + c4 * 4]) = v;
    }
    __syncthreads();
    for (int j4 = 0; j4 < 32; ++j4) {
      float4 mv = *(const float4*)(&mel_s[b * PADW + j4 * 4]);
      #pragma unroll
      for (int i = 0; i < 8; ++i) {
        int k = kb + (i << 3);
        float4 tv = *(const float4*)(&tgt_s[k * PADW + j4 * 4]);
        acc[i] += fabsf(mv.x - tv.x) + fabsf(mv.y - tv.y) +
                  fabsf(mv.z - tv.z) + fabsf(mv.w - tv.w);
      }
    }
  }

  #pragma unroll
  for (int i = 0; i < 8; ++i)
    part[(size_t)blockIdx.x * 2048 + b * 64 + kb + (i << 3)] = acc[i];
}

// ---------------------------------------------------------------------------
// Kernel C: reduce partials -> diffs (mean), min over targets.
// ---------------------------------------------------------------------------
__global__ __launch_bounds__(256) void reduce_kernel(
    const float* __restrict__ part, float* __restrict__ out) {
  __shared__ float ds[256];
  int tid = threadIdx.x;
  int p = blockIdx.x * 256 + tid;
  float s = 0.0f;
  for (int bb = 0; bb < NB_B; ++bb) s += part[(size_t)bb * 2048 + p];
  ds[tid] = s * (1.0f / (float)MELSZ);
  __syncthreads();
  if (tid < 4) {
    float mn = ds[tid * 64];
    #pragma unroll
    for (int kk = 1; kk < 64; ++kk) mn = fminf(mn, ds[tid * 64 + kk]);
    out[blockIdx.x * 4 + tid] = mn;
  }
}

// ---------------------------------------------------------------------------
extern "C" void kernel_launch(void* const* d_in, const int* in_sizes, int n_in,
                              void* d_out, int out_size, void* d_ws, size_t ws_size,
                              hipStream_t stream) {
  const float* x   = (const float*)d_in[0];   // (32, 48000)
  const float* tgt = (const float*)d_in[1];   // (64, 128, 751)
  const float* fb  = (const float*)d_in[2];   // (1025, 128)
  float* out = (float*)d_out;                 // (32,)

  char* ws = (char*)d_ws;
  size_t off = 0;
  float* fbT = (float*)(ws + off);
  off += ((size_t)NMELS * NFREQ * sizeof(float) + 255) & ~(size_t)255;
  int* fs = (int*)(ws + off); off += 1024;
  int* fe = (int*)(ws + off); off += 1024;
  float* wtab = (float*)(ws + off); off += NFFT * sizeof(float);
  float* gtwc = (float*)(ws + off); off += 1056 * sizeof(float);
  float* gtws = (float*)(ws + off); off += 1056 * sizeof(float);
  float* mel = (float*)(ws + off);
  off += (size_t)BATCH * MELSZ * sizeof(float);
  float* part = (float*)(ws + off);
  off += (size_t)NB_B * 2048 * sizeof(float);

  tab_kernel<<<8, 256, 0, stream>>>(wtab, gtwc, gtws);
  fbt_kernel<<<NMELS, 256, 0, stream>>>(fb, fbT, fs, fe);
  melspec_kernel<<<BATCH * NFRAMES, 256, 0, stream>>>(
      x, fbT, fs, fe, wtab, gtwc, gtws, mel);
  diff_kernel<<<NB_B, 256, 0, stream>>>(mel, tgt, part);
  reduce_kernel<<<8, 256, 0, stream>>>(part, out);
}

// Round 12
// 241.396 us; speedup vs baseline: 2.3365x; 1.2067x over previous
//
#include <hip/hip_runtime.h>
#include <math.h>

#define SRATE   48000
#define NFFT    2048
#define N1      1024          // half-size complex FFT per real frame
#define HOP     64
#define NMELS   128
#define NFREQ   1025          // NFFT/2 + 1
#define NTGT    64
#define BATCH   32
#define NFRAMES 751           // 1 + 48000/64
#define MELSZ   (NMELS * NFRAMES)   // 96128
#define NCHUNK  751
#define PADW    132           // padded LDS row stride (floats) in diff kernel

// Padded LDS index (verified: absmax 0.0 in rounds 10/11).
__device__ __forceinline__ int SP(int a) { return a + 5 * (a >> 5); }
#define SBUF1 1179            // SP(1023)+1
__device__ __forceinline__ int TP(int a) { return a + (a >> 5); }
#define TWP   263             // TP(255)+1

// ---------------------------------------------------------------------------
// Setup: Hann window as float2 pairs (wtab2[n] = {w[2n], w[2n+1]}) and
// twiddle table gtw[k] = {cos,sin}(-2*pi*k/2048), k <= 1024.
// ---------------------------------------------------------------------------
__global__ __launch_bounds__(256) void tab_kernel(
    float2* __restrict__ wtab2, float2* __restrict__ gtw) {
  int i = blockIdx.x * 256 + threadIdx.x;
  if (i < N1) {
    float w0 = 0.5f - 0.5f * cosf((float)(2.0 * M_PI / NFFT) * (float)(2 * i));
    float w1 = 0.5f - 0.5f * cosf((float)(2.0 * M_PI / NFFT) * (float)(2 * i + 1));
    wtab2[i] = make_float2(w0, w1);
  }
  if (i <= 1024) {
    float sv, cv;
    sincosf(-(float)(2.0 * M_PI / NFFT) * (float)i, &sv, &cv);
    gtw[i] = make_float2(cv, sv);
  }
}

// ---------------------------------------------------------------------------
// Kernel T: transpose fb -> fbT and exact nonzero f-range per mel filter.
// ---------------------------------------------------------------------------
__global__ __launch_bounds__(256) void fbt_kernel(
    const float* __restrict__ fb, float* __restrict__ fbT,
    int* __restrict__ fs, int* __restrict__ fe) {
  int m = blockIdx.x;
  int tid = threadIdx.x;
  __shared__ int smin[256], smax[256];
  int lmin = NFREQ, lmax = -1;
  for (int f = tid; f < NFREQ; f += 256) {
    float v = fb[f * NMELS + m];
    fbT[m * NFREQ + f] = v;
    if (v > 0.0f) {
      if (f < lmin) lmin = f;
      if (f > lmax) lmax = f;
    }
  }
  smin[tid] = lmin;
  smax[tid] = lmax;
  __syncthreads();
  for (int off = 128; off > 0; off >>= 1) {
    if (tid < off) {
      smin[tid] = min(smin[tid], smin[tid + off]);
      smax[tid] = max(smax[tid], smax[tid + off]);
    }
    __syncthreads();
  }
  if (tid == 0) {
    fs[m] = smin[0];
    fe[m] = smax[0];
  }
}

// ---------------------------------------------------------------------------
// Stockham radix-4 round, N=1024, float2-interleaved (re,im) LDS:
// 4 b64 reads + 4 b64 writes per butterfly (was 8+8 b32).
// ---------------------------------------------------------------------------
template<int L>
__device__ __forceinline__ void r4_1024(
    const float2* __restrict__ s, float2* __restrict__ d,
    const float2* __restrict__ tw, int t) {
  constexpr int LOG2L = (L == 1) ? 0 : (L == 4) ? 2 : (L == 16) ? 4
                      : (L == 64) ? 6 : 8;
  constexpr int TS = 256 / L;
  int k = t & (L - 1);
  int j = t >> LOG2L;
  int rb = SP(t);
  float2 u0 = s[rb], u1 = s[rb + 296], u2 = s[rb + 592], u3 = s[rb + 888];
  float a1r, a1i, a2r, a2i, a3r, a3i;
  if (L == 1) {
    a1r = u1.x; a1i = u1.y; a2r = u2.x; a2i = u2.y; a3r = u3.x; a3i = u3.y;
  } else {
    float2 w = tw[TP(k * TS)];
    float wc1 = w.x, ws1 = w.y;
    float wc2 = wc1 * wc1 - ws1 * ws1, ws2 = 2.0f * wc1 * ws1;
    float wc3 = wc2 * wc1 - ws2 * ws1, ws3 = wc2 * ws1 + ws2 * wc1;
    a1r = wc1 * u1.x - ws1 * u1.y; a1i = wc1 * u1.y + ws1 * u1.x;
    a2r = wc2 * u2.x - ws2 * u2.y; a2i = wc2 * u2.y + ws2 * u2.x;
    a3r = wc3 * u3.x - ws3 * u3.y; a3i = wc3 * u3.y + ws3 * u3.x;
  }
  float s0r = u0.x + a2r, s0i = u0.y + a2i;
  float d0r = u0.x - a2r, d0i = u0.y - a2i;
  float s1r = a1r + a3r, s1i = a1i + a3i;
  float d1r = a1r - a3r, d1i = a1i - a3i;
  int wb = (j << (LOG2L + 2)) + k;
  d[SP(wb)]         = make_float2(s0r + s1r, s0i + s1i);
  d[SP(wb + L)]     = make_float2(d0r + d1i, d0i - d1r);
  d[SP(wb + 2 * L)] = make_float2(s0r - s1r, s0i - s1i);
  d[SP(wb + 3 * L)] = make_float2(d0r - d1i, d0i + d1r);
}

// ---------------------------------------------------------------------------
// Kernel A: one block per (batch, frame). Even/odd-packed 1024-pt complex
// Stockham FFT (float2 LDS, 20.9 KB -> 7 blocks/CU), conjugate-symmetry
// post-twiddle unpack to powers, sparse mel projection (2 threads/filter).
// ---------------------------------------------------------------------------
__global__ __launch_bounds__(256) void melspec_kernel(
    const float* __restrict__ x, const float* __restrict__ fbT,
    const int* __restrict__ fs, const int* __restrict__ fe,
    const float2* __restrict__ wtab2, const float2* __restrict__ gtw,
    float* __restrict__ mel) {
  __shared__ float2 zA[SBUF1];
  __shared__ float2 zB[SBUF1];
  __shared__ float2 twl[TWP];   // total 20968 B

  int tid = threadIdx.x;
  int b = blockIdx.x / NFRAMES;
  int t = blockIdx.x - b * NFRAMES;
  const float* xb = x + (size_t)b * SRATE;

  // stage W_1024 round twiddles: W_1024^j = W_2048^{2j}
  twl[TP(tid)] = gtw[2 * tid];

  // load frame: z[n] = xw[2n] + i*xw[2n+1]; float2 global loads on the
  // (overwhelmingly common) non-reflected path.
  int base = t * HOP - NFFT / 2;
  for (int n = tid; n < N1; n += 256) {
    int p0 = base + 2 * n;
    float2 v;
    if (p0 >= 0 && p0 + 1 < SRATE) {
      v = *(const float2*)(xb + p0);
    } else {
      int q0 = p0 < 0 ? -p0 : (p0 >= SRATE ? 2 * SRATE - 2 - p0 : p0);
      int p1 = p0 + 1;
      int q1 = p1 < 0 ? -p1 : (p1 >= SRATE ? 2 * SRATE - 2 - p1 : p1);
      v = make_float2(xb[q0], xb[q1]);
    }
    float2 w2 = wtab2[n];
    zA[SP(n)] = make_float2(v.x * w2.x, v.y * w2.y);
  }
  __syncthreads();

  r4_1024<1>(zA, zB, twl, tid);   __syncthreads();
  r4_1024<4>(zB, zA, twl, tid);   __syncthreads();
  r4_1024<16>(zA, zB, twl, tid);  __syncthreads();
  r4_1024<64>(zB, zA, twl, tid);  __syncthreads();
  r4_1024<256>(zA, zB, twl, tid); __syncthreads();
  // natural-order Z in zB; zA free -> reuse as plain-indexed power array

  float* pw = (float*)zA;   // 2358 floats capacity >= 1025
  for (int k = tid; k <= 1024; k += 256) {
    int ka = SP(k & (N1 - 1)), kb = SP((N1 - k) & (N1 - 1));
    float2 Za = zB[ka], Zb = zB[kb];
    float Xer  = 0.5f * (Za.x + Zb.x), Xei = 0.5f * (Za.y - Zb.y);
    float Xor_ = 0.5f * (Za.y + Zb.y), Xoi = 0.5f * (Zb.x - Za.x);
    float2 w = gtw[k];
    float Xr = Xer + w.x * Xor_ - w.y * Xoi;
    float Xi = Xei + w.x * Xoi + w.y * Xor_;
    pw[k] = Xr * Xr + Xi * Xi;
  }
  __syncthreads();

  // sparse mel projection: 2 threads per filter, shuffle-combine
  int m = tid >> 1, half = tid & 1;
  int f0 = fs[m], f1 = fe[m];
  int mid = f0 + ((f1 - f0 + 1) >> 1);
  int lo = half ? mid : f0;
  int hi = half ? f1 : mid - 1;
  const float* col = fbT + (size_t)m * NFREQ;
  float acc = 0.0f;
  for (int f = lo; f <= hi; ++f) acc += pw[f] * col[f];
  acc += __shfl_xor(acc, 1);
  if (!half) mel[(size_t)b * MELSZ + m * NFRAMES + t] = acc;
}

// ---------------------------------------------------------------------------
// Kernel B: L1-distance partials, one 128-elem chunk per block; 2b x 4k per
// thread (6 b128 LDS reads per j4 instead of 9); per-block partial summed
// straight into diffs[2048] via atomicAdd (no part round-trip).
// ---------------------------------------------------------------------------
__global__ __launch_bounds__(256) void diff_kernel(
    const float* __restrict__ mel, const float* __restrict__ tgt,
    float* __restrict__ diffs) {
  __shared__ float mel_s[BATCH * PADW];
  __shared__ float tgt_s[NTGT * PADW];
  int tid = threadIdx.x;
  int bg = tid >> 4;        // 0..15 -> b in {2bg, 2bg+1}
  int kg = tid & 15;        // 0..15 -> k in {kg + 16i}, i<4
  int c = blockIdx.x;

  // stage mel chunk: 32 rows x 128 floats
  for (int q = tid; q < BATCH * 32; q += 256) {
    int row = q >> 5, c4 = q & 31;
    float4 v = *(const float4*)(mel + (size_t)row * MELSZ + c * 128 + c4 * 4);
    *(float4*)(&mel_s[row * PADW + c4 * 4]) = v;
  }
  // stage target chunk: 64 rows x 128 floats
  for (int q = tid; q < NTGT * 32; q += 256) {
    int row = q >> 5, c4 = q & 31;
    float4 v = *(const float4*)(tgt + (size_t)row * MELSZ + c * 128 + c4 * 4);
    *(float4*)(&tgt_s[row * PADW + c4 * 4]) = v;
  }
  __syncthreads();

  float acc[2][4];
  #pragma unroll
  for (int bi = 0; bi < 2; ++bi)
    #pragma unroll
    for (int i = 0; i < 4; ++i) acc[bi][i] = 0.0f;

  for (int j4 = 0; j4 < 32; ++j4) {
    float4 m0 = *(const float4*)(&mel_s[(2 * bg) * PADW + j4 * 4]);
    float4 m1 = *(const float4*)(&mel_s[(2 * bg + 1) * PADW + j4 * 4]);
    #pragma unroll
    for (int i = 0; i < 4; ++i) {
      int k = kg + (i << 4);
      float4 tv = *(const float4*)(&tgt_s[k * PADW + j4 * 4]);
      acc[0][i] += fabsf(m0.x - tv.x) + fabsf(m0.y - tv.y) +
                   fabsf(m0.z - tv.z) + fabsf(m0.w - tv.w);
      acc[1][i] += fabsf(m1.x - tv.x) + fabsf(m1.y - tv.y) +
                   fabsf(m1.z - tv.z) + fabsf(m1.w - tv.w);
    }
  }

  #pragma unroll
  for (int bi = 0; bi < 2; ++bi)
    #pragma unroll
    for (int i = 0; i < 4; ++i)
      atomicAdd(&diffs[(2 * bg + bi) * 64 + kg + (i << 4)], acc[bi][i]);
}

// ---------------------------------------------------------------------------
// Kernel C: scale diffs by 1/MELSZ, min over 64 targets per batch row.
// ---------------------------------------------------------------------------
__global__ __launch_bounds__(256) void reduce_kernel(
    const float* __restrict__ diffs, float* __restrict__ out) {
  __shared__ float ds[256];
  int tid = threadIdx.x;
  int p = blockIdx.x * 256 + tid;
  ds[tid] = diffs[p] * (1.0f / (float)MELSZ);
  __syncthreads();
  if (tid < 4) {
    float mn = ds[tid * 64];
    #pragma unroll
    for (int kk = 1; kk < 64; ++kk) mn = fminf(mn, ds[tid * 64 + kk]);
    out[blockIdx.x * 4 + tid] = mn;
  }
}

// ---------------------------------------------------------------------------
extern "C" void kernel_launch(void* const* d_in, const int* in_sizes, int n_in,
                              void* d_out, int out_size, void* d_ws, size_t ws_size,
                              hipStream_t stream) {
  const float* x   = (const float*)d_in[0];   // (32, 48000)
  const float* tgt = (const float*)d_in[1];   // (64, 128, 751)
  const float* fb  = (const float*)d_in[2];   // (1025, 128)
  float* out = (float*)d_out;                 // (32,)

  char* ws = (char*)d_ws;
  size_t off = 0;
  float* fbT = (float*)(ws + off);
  off += ((size_t)NMELS * NFREQ * sizeof(float) + 255) & ~(size_t)255;
  int* fs = (int*)(ws + off); off += 1024;
  int* fe = (int*)(ws + off); off += 1024;
  float2* wtab2 = (float2*)(ws + off); off += N1 * sizeof(float2);
  float2* gtw   = (float2*)(ws + off); off += 1056 * sizeof(float2);
  float* mel = (float*)(ws + off);
  off += (size_t)BATCH * MELSZ * sizeof(float);
  float* diffs = (float*)(ws + off); off += 2048 * sizeof(float);

  hipMemsetAsync(diffs, 0, 2048 * sizeof(float), stream);
  tab_kernel<<<8, 256, 0, stream>>>(wtab2, gtw);
  fbt_kernel<<<NMELS, 256, 0, stream>>>(fb, fbT, fs, fe);
  melspec_kernel<<<BATCH * NFRAMES, 256, 0, stream>>>(
      x, fbT, fs, fe, wtab2, gtw, mel);
  diff_kernel<<<NCHUNK, 256, 0, stream>>>(mel, tgt, diffs);
  reduce_kernel<<<8, 256, 0, stream>>>(diffs, out);
}